// Round 1
// baseline (861.260 us; speedup 1.0000x reference)
//
#include <hip/hip_runtime.h>

#define N_NODES 50000
#define N_EDGES 800000
#define FDIM 64

// ---------------- edge weight + CSR construction ----------------

__global__ __launch_bounds__(256) void hist_kernel(const int* __restrict__ row,
                                                   int* __restrict__ cnt, int E) {
  int e = blockIdx.x * 256 + threadIdx.x;
  if (e < E) atomicAdd(&cnt[row[e]], 1);
}

__global__ __launch_bounds__(1024) void prefix_kernel(int* __restrict__ cnt,
                                                      int* __restrict__ offs,
                                                      int n, int E) {
  __shared__ int tot[1024];
  int t = threadIdx.x;
  int CH = (n + 1023) >> 10;
  int b = t * CH;
  int e = min(b + CH, n);
  int s = 0;
  for (int i = b; i < e; ++i) s += cnt[i];
  tot[t] = s;
  __syncthreads();
  for (int d = 1; d < 1024; d <<= 1) {
    int add = (t >= d) ? tot[t - d] : 0;
    __syncthreads();
    tot[t] += add;
    __syncthreads();
  }
  int run = (t == 0) ? 0 : tot[t - 1];
  for (int i = b; i < e; ++i) {
    int h = cnt[i];
    offs[i] = run;
    cnt[i] = run;  // becomes the scatter cursor
    run += h;
  }
  if (t == 0) offs[n] = E;
}

__global__ __launch_bounds__(256) void scatter_kernel(
    const int* __restrict__ row, const int* __restrict__ col,
    const float* __restrict__ ent, const float* __restrict__ ccf,
    const float* __restrict__ wsym, const float* __restrict__ encw,
    const float* __restrict__ encb, const float* __restrict__ q,
    int* __restrict__ cursor, int* __restrict__ col_s,
    float* __restrict__ wr_s, float* __restrict__ wi_s, int E) {
  int e = blockIdx.x * 256 + threadIdx.x;
  if (e >= E) return;
  float se = encw[0] * ent[e] + encw[1] * ccf[e] + encb[0];
  float ph = q[0] * se;
  float sw, cw;
  sincosf(ph, &sw, &cw);
  float w = wsym[e];
  int pos = atomicAdd(&cursor[row[e]], 1);
  col_s[pos] = col[e];
  wr_s[pos] = w * cw;
  wi_s[pos] = w * sw;
}

// ---------------- weight transpose prep ----------------

__global__ __launch_bounds__(256) void prep_weights(
    const float* __restrict__ r0, const float* __restrict__ i0,
    const float* __restrict__ r1, const float* __restrict__ i1,
    const float* __restrict__ ow, float* __restrict__ r0T,
    float* __restrict__ i0T, float* __restrict__ r1T, float* __restrict__ i1T,
    float* __restrict__ owT) {
  int t = blockIdx.x * 256 + threadIdx.x;
  if (t < 128 * 64) {  // [128 h][64 f] -> [64 f][128 h]
    int h = t / 64, f = t % 64;
    r0T[f * 128 + h] = r0[t];
    i0T[f * 128 + h] = i0[t];
  }
  if (t < 128 * 128) {  // [128 h][128 f] -> [128 f][128 h]
    int h = t / 128, f = t % 128;
    r1T[f * 128 + h] = r1[t];
    i1T[f * 128 + h] = i1[t];
  }
  if (t < 32 * 256) {  // [32 o][256 f] -> [256 f][32 o]
    int o = t / 256, f = t % 256;
    owT[f * 32 + o] = ow[t];
  }
}

// ---------------- complex propagation (one wave per dest node) ----------------

__global__ __launch_bounds__(256) void prop_kernel(
    const float* __restrict__ xr, const float* __restrict__ xi,
    float* __restrict__ yr, float* __restrict__ yi,
    const int* __restrict__ offs, const int* __restrict__ col_s,
    const float* __restrict__ wr_s, const float* __restrict__ wi_s, int n) {
  int wave = (int)((blockIdx.x * (size_t)blockDim.x + threadIdx.x) >> 6);
  int lane = threadIdx.x & 63;
  if (wave >= n) return;
  int beg = offs[wave], end = offs[wave + 1];
  float accR = 0.f, accI = 0.f;
  for (int j = beg; j < end; ++j) {
    float wr = wr_s[j];
    float wi = wi_s[j];
    int c = col_s[j];
    float xrv = xr[(size_t)c * FDIM + lane];
    float xiv = xi[(size_t)c * FDIM + lane];
    accR += wr * xrv - wi * xiv;
    accI += wi * xrv + wr * xiv;
  }
  yr[(size_t)wave * FDIM + lane] = accR;
  yi[(size_t)wave * FDIM + lane] = accI;
}

// ---------------- fused attention pooling + complex MLP + output ----------------

__device__ __forceinline__ float wave_sum(float v) {
#pragma unroll
  for (int d = 32; d > 0; d >>= 1) v += __shfl_xor(v, d, 64);
  return v;
}

__global__ __launch_bounds__(256) void head_kernel(
    const float* __restrict__ R0, const float* __restrict__ R1,
    const float* __restrict__ R2, const float* __restrict__ R3,
    const float* __restrict__ I0, const float* __restrict__ I1,
    const float* __restrict__ I2, const float* __restrict__ I3,
    const float* __restrict__ rattw, const float* __restrict__ rattb,
    const float* __restrict__ iattw, const float* __restrict__ iattb,
    const float* __restrict__ r0T, const float* __restrict__ r0b,
    const float* __restrict__ i0T, const float* __restrict__ i0b,
    const float* __restrict__ r1T, const float* __restrict__ r1b,
    const float* __restrict__ i1T, const float* __restrict__ i1b,
    const float* __restrict__ owT, const float* __restrict__ ob,
    float* __restrict__ out, int n) {
  int wave = (int)((blockIdx.x * (size_t)blockDim.x + threadIdx.x) >> 6);
  int lane = threadIdx.x & 63;
  if (wave >= n) return;
  size_t base = (size_t)wave * FDIM + lane;
  float r0 = R0[base], r1 = R1[base], r2 = R2[base], r3 = R3[base];
  float i0 = I0[base], i1 = I1[base], i2 = I2[base], i3 = I3[base];
  float aw = rattw[lane], bw = iattw[lane];

  float ra0 = wave_sum(r0 * aw) + rattb[0];
  float ra1 = wave_sum(r1 * aw) + rattb[0];
  float ra2 = wave_sum(r2 * aw) + rattb[0];
  float ra3 = wave_sum(r3 * aw) + rattb[0];
  float ia0 = wave_sum(i0 * bw) + iattb[0];
  float ia1 = wave_sum(i1 * bw) + iattb[0];
  float ia2 = wave_sum(i2 * bw) + iattb[0];
  float ia3 = wave_sum(i3 * bw) + iattb[0];

  // sigmoid
  float s0 = 1.f / (1.f + expf(-ra0));
  float s1 = 1.f / (1.f + expf(-ra1));
  float s2 = 1.f / (1.f + expf(-ra2));
  float s3 = 1.f / (1.f + expf(-ra3));
  float t0 = 1.f / (1.f + expf(-ia0));
  float t1 = 1.f / (1.f + expf(-ia1));
  float t2 = 1.f / (1.f + expf(-ia2));
  float t3 = 1.f / (1.f + expf(-ia3));
  // softmax over the 4 step values
  float mR = fmaxf(fmaxf(s0, s1), fmaxf(s2, s3));
  float e0 = expf(s0 - mR), e1 = expf(s1 - mR), e2 = expf(s2 - mR), e3 = expf(s3 - mR);
  float invR = 1.f / (e0 + e1 + e2 + e3);
  float mI = fmaxf(fmaxf(t0, t1), fmaxf(t2, t3));
  float g0 = expf(t0 - mI), g1 = expf(t1 - mI), g2 = expf(t2 - mI), g3 = expf(t3 - mI);
  float invI = 1.f / (g0 + g1 + g2 + g3);

  float pr = (r0 * e0 + r1 * e1 + r2 * e2 + r3 * e3) * invR;
  float pi = (i0 * g0 + i1 * g1 + i2 * g2 + i3 * g3) * invI;

  // ---- layer 0: F=64 -> H=128, lane holds h=lane and h=lane+64 ----
  float zr0 = r0b[lane], zr1 = r0b[64 + lane];
  float zi0 = i0b[lane], zi1 = i0b[64 + lane];
  for (int f = 0; f < 64; ++f) {
    float prf = __shfl(pr, f, 64);
    float pif = __shfl(pi, f, 64);
    zr0 += prf * r0T[f * 128 + lane];
    zr1 += prf * r0T[f * 128 + 64 + lane];
    zi0 += pif * i0T[f * 128 + lane];
    zi1 += pif * i0T[f * 128 + 64 + lane];
  }
  float m0 = (zr0 >= 0.f) ? 1.f : 0.f;
  float m1 = (zr1 >= 0.f) ? 1.f : 0.f;
  float xr0 = zr0 * m0, xr1 = zr1 * m1, xi0 = zi0 * m0, xi1 = zi1 * m1;

  // ---- layer 1: 128 -> 128 ----
  float yr0 = r1b[lane], yr1 = r1b[64 + lane];
  float yi0 = i1b[lane], yi1 = i1b[64 + lane];
  for (int f = 0; f < 64; ++f) {
    float ar = __shfl(xr0, f, 64), ai = __shfl(xi0, f, 64);
    yr0 += ar * r1T[f * 128 + lane];
    yr1 += ar * r1T[f * 128 + 64 + lane];
    yi0 += ai * i1T[f * 128 + lane];
    yi1 += ai * i1T[f * 128 + 64 + lane];
  }
  for (int f = 0; f < 64; ++f) {
    float ar = __shfl(xr1, f, 64), ai = __shfl(xi1, f, 64);
    yr0 += ar * r1T[(64 + f) * 128 + lane];
    yr1 += ar * r1T[(64 + f) * 128 + 64 + lane];
    yi0 += ai * i1T[(64 + f) * 128 + lane];
    yi1 += ai * i1T[(64 + f) * 128 + 64 + lane];
  }
  m0 = (yr0 >= 0.f) ? 1.f : 0.f;
  m1 = (yr1 >= 0.f) ? 1.f : 0.f;
  float fr0 = yr0 * m0, fr1 = yr1 * m1, fi0 = yi0 * m0, fi1 = yi1 * m1;

  // ---- output: concat(real,imag) 256 -> 32; lanes<32 take f<128, lanes>=32 f>=128 ----
  int o = lane & 31, hi = lane >> 5;
  float acc = 0.f;
  for (int f = 0; f < 64; ++f) {
    float vr = __shfl(fr0, f, 64);
    float vi = __shfl(fi0, f, 64);
    acc += (hi ? vi : vr) * owT[(hi ? 128 + f : f) * 32 + o];
  }
  for (int f = 0; f < 64; ++f) {
    float vr = __shfl(fr1, f, 64);
    float vi = __shfl(fi1, f, 64);
    acc += (hi ? vi : vr) * owT[(hi ? 192 + f : 64 + f) * 32 + o];
  }
  acc += __shfl_xor(acc, 32, 64);
  if (lane < 32) out[(size_t)wave * 32 + o] = acc + ob[o];
}

// ---------------- launch ----------------

extern "C" void kernel_launch(void* const* d_in, const int* in_sizes, int n_in,
                              void* d_out, int out_size, void* d_ws,
                              size_t ws_size, hipStream_t stream) {
  const float* realf = (const float*)d_in[0];
  const float* imagf = (const float*)d_in[1];
  const float* ent = (const float*)d_in[2];
  const float* ccf = (const float*)d_in[3];
  const float* wsym = (const float*)d_in[4];
  const float* q = (const float*)d_in[5];
  const float* encw = (const float*)d_in[6];
  const float* encb = (const float*)d_in[7];
  const float* rattw = (const float*)d_in[8];
  const float* rattb = (const float*)d_in[9];
  const float* iattw = (const float*)d_in[10];
  const float* iattb = (const float*)d_in[11];
  const float* r0w = (const float*)d_in[12];
  const float* r0b = (const float*)d_in[13];
  const float* r1w = (const float*)d_in[14];
  const float* r1b = (const float*)d_in[15];
  const float* i0w = (const float*)d_in[16];
  const float* i0b = (const float*)d_in[17];
  const float* i1w = (const float*)d_in[18];
  const float* i1b = (const float*)d_in[19];
  const float* ow = (const float*)d_in[20];
  const float* ob = (const float*)d_in[21];
  const int* row = (const int*)d_in[22];
  const int* col = (const int*)d_in[23];
  float* out = (float*)d_out;

  char* p = (char*)d_ws;
  auto alloc = [&](size_t bytes) -> void* {
    void* r = (void*)p;
    p += (bytes + 255) & ~(size_t)255;
    return r;
  };
  int* cnt = (int*)alloc(N_NODES * sizeof(int));
  int* offs = (int*)alloc((N_NODES + 1) * sizeof(int));
  int* col_s = (int*)alloc(N_EDGES * sizeof(int));
  float* wr_s = (float*)alloc(N_EDGES * sizeof(float));
  float* wi_s = (float*)alloc(N_EDGES * sizeof(float));
  size_t NF = (size_t)N_NODES * FDIM;
  float* R1 = (float*)alloc(NF * 4);
  float* R2 = (float*)alloc(NF * 4);
  float* R3 = (float*)alloc(NF * 4);
  float* I1 = (float*)alloc(NF * 4);
  float* I2 = (float*)alloc(NF * 4);
  float* I3 = (float*)alloc(NF * 4);
  float* r0T = (float*)alloc(64 * 128 * 4);
  float* i0T = (float*)alloc(64 * 128 * 4);
  float* r1T = (float*)alloc(128 * 128 * 4);
  float* i1T = (float*)alloc(128 * 128 * 4);
  float* owT = (float*)alloc(256 * 32 * 4);

  hipMemsetAsync(cnt, 0, N_NODES * sizeof(int), stream);
  prep_weights<<<64, 256, 0, stream>>>(r0w, i0w, r1w, i1w, ow, r0T, i0T, r1T,
                                       i1T, owT);
  hist_kernel<<<(N_EDGES + 255) / 256, 256, 0, stream>>>(row, cnt, N_EDGES);
  prefix_kernel<<<1, 1024, 0, stream>>>(cnt, offs, N_NODES, N_EDGES);
  scatter_kernel<<<(N_EDGES + 255) / 256, 256, 0, stream>>>(
      row, col, ent, ccf, wsym, encw, encb, q, cnt, col_s, wr_s, wi_s, N_EDGES);

  const int pgrid = (N_NODES + 3) / 4;  // 4 waves (nodes) per 256-thread block
  prop_kernel<<<pgrid, 256, 0, stream>>>(realf, imagf, R1, I1, offs, col_s,
                                         wr_s, wi_s, N_NODES);
  prop_kernel<<<pgrid, 256, 0, stream>>>(R1, I1, R2, I2, offs, col_s, wr_s,
                                         wi_s, N_NODES);
  prop_kernel<<<pgrid, 256, 0, stream>>>(R2, I2, R3, I3, offs, col_s, wr_s,
                                         wi_s, N_NODES);

  head_kernel<<<pgrid, 256, 0, stream>>>(
      realf, R1, R2, R3, imagf, I1, I2, I3, rattw, rattb, iattw, iattb, r0T,
      r0b, i0T, i0b, r1T, r1b, i1T, i1b, owT, ob, out, N_NODES);
}

// Round 2
// 791.586 us; speedup vs baseline: 1.0880x; 1.0880x over previous
//
#include <hip/hip_runtime.h>

#define N_NODES 50000
#define N_EDGES 800000
#define FDIM 64

// ---------------- edge weight + CSR construction ----------------

__global__ __launch_bounds__(256) void hist_kernel(const int* __restrict__ row,
                                                   int* __restrict__ cnt, int E) {
  int e = blockIdx.x * 256 + threadIdx.x;
  if (e < E) atomicAdd(&cnt[row[e]], 1);
}

__global__ __launch_bounds__(1024) void prefix_kernel(int* __restrict__ cnt,
                                                      int* __restrict__ offs,
                                                      int n, int E) {
  __shared__ int tot[1024];
  int t = threadIdx.x;
  int CH = (n + 1023) >> 10;
  int b = t * CH;
  int e = min(b + CH, n);
  int s = 0;
  for (int i = b; i < e; ++i) s += cnt[i];
  tot[t] = s;
  __syncthreads();
  for (int d = 1; d < 1024; d <<= 1) {
    int add = (t >= d) ? tot[t - d] : 0;
    __syncthreads();
    tot[t] += add;
    __syncthreads();
  }
  int run = (t == 0) ? 0 : tot[t - 1];
  for (int i = b; i < e; ++i) {
    int h = cnt[i];
    offs[i] = run;
    cnt[i] = run;  // becomes the scatter cursor
    run += h;
  }
  if (t == 0) offs[n] = E;
}

__global__ __launch_bounds__(256) void scatter_kernel(
    const int* __restrict__ row, const int* __restrict__ col,
    const float* __restrict__ ent, const float* __restrict__ ccf,
    const float* __restrict__ wsym, const float* __restrict__ encw,
    const float* __restrict__ encb, const float* __restrict__ q,
    int* __restrict__ cursor, int* __restrict__ col_s,
    float* __restrict__ wr_s, float* __restrict__ wi_s, int E) {
  int e = blockIdx.x * 256 + threadIdx.x;
  if (e >= E) return;
  float se = encw[0] * ent[e] + encw[1] * ccf[e] + encb[0];
  float ph = q[0] * se;
  float sw, cw;
  sincosf(ph, &sw, &cw);
  float w = wsym[e];
  int pos = atomicAdd(&cursor[row[e]], 1);
  col_s[pos] = col[e];
  wr_s[pos] = w * cw;
  wi_s[pos] = w * sw;
}

// ---------------- weight transpose prep ----------------

__global__ __launch_bounds__(256) void prep_weights(
    const float* __restrict__ r0, const float* __restrict__ i0,
    const float* __restrict__ r1, const float* __restrict__ i1,
    const float* __restrict__ ow, float* __restrict__ r0T,
    float* __restrict__ i0T, float* __restrict__ r1T, float* __restrict__ i1T,
    float* __restrict__ owT) {
  int t = blockIdx.x * 256 + threadIdx.x;
  if (t < 128 * 64) {  // [128 h][64 f] -> [64 f][128 h]
    int h = t / 64, f = t % 64;
    r0T[f * 128 + h] = r0[t];
    i0T[f * 128 + h] = i0[t];
  }
  if (t < 128 * 128) {  // [128 h][128 f] -> [128 f][128 h]
    int h = t / 128, f = t % 128;
    r1T[f * 128 + h] = r1[t];
    i1T[f * 128 + h] = i1[t];
  }
  if (t < 32 * 256) {  // [32 o][256 f] -> [256 f][32 o]
    int o = t / 256, f = t % 256;
    owT[f * 32 + o] = ow[t];
  }
}

// ---------------- complex propagation (one wave per dest node) ----------------

__global__ __launch_bounds__(256) void prop_kernel(
    const float* __restrict__ xr, const float* __restrict__ xi,
    float* __restrict__ yr, float* __restrict__ yi,
    const int* __restrict__ offs, const int* __restrict__ col_s,
    const float* __restrict__ wr_s, const float* __restrict__ wi_s, int n) {
  int wave = (int)((blockIdx.x * (size_t)blockDim.x + threadIdx.x) >> 6);
  int lane = threadIdx.x & 63;
  if (wave >= n) return;
  int beg = offs[wave], end = offs[wave + 1];
  float accR = 0.f, accI = 0.f;
  for (int j = beg; j < end; ++j) {
    float wr = wr_s[j];
    float wi = wi_s[j];
    int c = col_s[j];
    float xrv = xr[(size_t)c * FDIM + lane];
    float xiv = xi[(size_t)c * FDIM + lane];
    accR += wr * xrv - wi * xiv;
    accI += wi * xrv + wr * xiv;
  }
  yr[(size_t)wave * FDIM + lane] = accR;
  yi[(size_t)wave * FDIM + lane] = accI;
}

// ---------------- fused attention pooling + complex MLP + output ----------------
// 8 nodes per wave: weight rows loaded once per f serve 8 nodes (8x less L2
// traffic). Activations broadcast via wave-private LDS with uniform-address
// ds_read_b128 (2 nodes re+im per read). No __syncthreads needed.

__device__ __forceinline__ float wave_sum(float v) {
#pragma unroll
  for (int d = 32; d > 0; d >>= 1) v += __shfl_xor(v, d, 64);
  return v;
}

__global__ __launch_bounds__(256) void head_kernel(
    const float* __restrict__ R0, const float* __restrict__ R1,
    const float* __restrict__ R2, const float* __restrict__ R3,
    const float* __restrict__ I0, const float* __restrict__ I1,
    const float* __restrict__ I2, const float* __restrict__ I3,
    const float* __restrict__ rattw, const float* __restrict__ rattb,
    const float* __restrict__ iattw, const float* __restrict__ iattb,
    const float* __restrict__ r0T, const float* __restrict__ r0b,
    const float* __restrict__ i0T, const float* __restrict__ i0b,
    const float* __restrict__ r1T, const float* __restrict__ r1b,
    const float* __restrict__ i1T, const float* __restrict__ i1b,
    const float* __restrict__ owT, const float* __restrict__ ob,
    float* __restrict__ out, int n) {
  __shared__ float4 act[4][512];  // 8 KB per wave, wave-private
  int wid = threadIdx.x >> 6;
  int lane = threadIdx.x & 63;
  int wave = blockIdx.x * 4 + wid;
  int nb = wave * 8;
  if (nb >= n) return;  // whole-wave guard (n % 8 == 0)
  float4* A = act[wid];

  float aw = rattw[lane], bw = iattw[lane];
  float rb0 = rattb[0], ib0 = iattb[0];
  float pr[8], pi[8];
#pragma unroll
  for (int k = 0; k < 8; ++k) {
    size_t base = (size_t)(nb + k) * FDIM + lane;
    float r0 = R0[base], r1 = R1[base], r2 = R2[base], r3 = R3[base];
    float q0 = I0[base], q1 = I1[base], q2 = I2[base], q3 = I3[base];
    float ra0 = wave_sum(r0 * aw) + rb0;
    float ra1 = wave_sum(r1 * aw) + rb0;
    float ra2 = wave_sum(r2 * aw) + rb0;
    float ra3 = wave_sum(r3 * aw) + rb0;
    float ia0 = wave_sum(q0 * bw) + ib0;
    float ia1 = wave_sum(q1 * bw) + ib0;
    float ia2 = wave_sum(q2 * bw) + ib0;
    float ia3 = wave_sum(q3 * bw) + ib0;
    float s0 = 1.f / (1.f + __expf(-ra0));
    float s1 = 1.f / (1.f + __expf(-ra1));
    float s2 = 1.f / (1.f + __expf(-ra2));
    float s3 = 1.f / (1.f + __expf(-ra3));
    float t0 = 1.f / (1.f + __expf(-ia0));
    float t1 = 1.f / (1.f + __expf(-ia1));
    float t2 = 1.f / (1.f + __expf(-ia2));
    float t3 = 1.f / (1.f + __expf(-ia3));
    float mR = fmaxf(fmaxf(s0, s1), fmaxf(s2, s3));
    float e0 = expf(s0 - mR), e1 = expf(s1 - mR), e2 = expf(s2 - mR),
          e3 = expf(s3 - mR);
    float invR = 1.f / (e0 + e1 + e2 + e3);
    float mI = fmaxf(fmaxf(t0, t1), fmaxf(t2, t3));
    float g0 = expf(t0 - mI), g1 = expf(t1 - mI), g2 = expf(t2 - mI),
          g3 = expf(t3 - mI);
    float invI = 1.f / (g0 + g1 + g2 + g3);
    pr[k] = (r0 * e0 + r1 * e1 + r2 * e2 + r3 * e3) * invR;
    pi[k] = (q0 * g0 + q1 * g1 + q2 * g2 + q3 * g3) * invI;
  }

  // stage pooled activations: entry(f, k2) = (pr[2k2], pi[2k2], pr[2k2+1], pi[2k2+1])
#pragma unroll
  for (int k2 = 0; k2 < 4; ++k2)
    A[k2 * 64 + lane] =
        make_float4(pr[2 * k2], pi[2 * k2], pr[2 * k2 + 1], pi[2 * k2 + 1]);

  // ---- layer 0: 64 -> 128, lane holds h=lane and h=lane+64 ----
  float br0 = r0b[lane], br1 = r0b[64 + lane];
  float bi0 = i0b[lane], bi1 = i0b[64 + lane];
  float zr0[8], zr1[8], zi0[8], zi1[8];
#pragma unroll
  for (int k = 0; k < 8; ++k) {
    zr0[k] = br0; zr1[k] = br1; zi0[k] = bi0; zi1[k] = bi1;
  }
#pragma unroll 8
  for (int f = 0; f < 64; ++f) {
    float wa = r0T[f * 128 + lane], wb = r0T[f * 128 + 64 + lane];
    float wc = i0T[f * 128 + lane], wd = i0T[f * 128 + 64 + lane];
#pragma unroll
    for (int k2 = 0; k2 < 4; ++k2) {
      float4 v = A[k2 * 64 + f];  // uniform addr -> broadcast
      zr0[2 * k2] += v.x * wa; zr1[2 * k2] += v.x * wb;
      zi0[2 * k2] += v.y * wc; zi1[2 * k2] += v.y * wd;
      zr0[2 * k2 + 1] += v.z * wa; zr1[2 * k2 + 1] += v.z * wb;
      zi0[2 * k2 + 1] += v.w * wc; zi1[2 * k2 + 1] += v.w * wd;
    }
  }
#pragma unroll
  for (int k = 0; k < 8; ++k) {
    float m0 = (zr0[k] >= 0.f) ? 1.f : 0.f;
    float m1 = (zr1[k] >= 0.f) ? 1.f : 0.f;
    zr0[k] *= m0; zi0[k] *= m0; zr1[k] *= m1; zi1[k] *= m1;
  }

  // stage layer-1 inputs: entry(f2, k2), f2 in [0,128)
#pragma unroll
  for (int k2 = 0; k2 < 4; ++k2) {
    A[k2 * 128 + lane] =
        make_float4(zr0[2 * k2], zi0[2 * k2], zr0[2 * k2 + 1], zi0[2 * k2 + 1]);
    A[k2 * 128 + 64 + lane] =
        make_float4(zr1[2 * k2], zi1[2 * k2], zr1[2 * k2 + 1], zi1[2 * k2 + 1]);
  }

  // ---- layer 1: 128 -> 128 ----
  float cr0 = r1b[lane], cr1 = r1b[64 + lane];
  float ci0 = i1b[lane], ci1 = i1b[64 + lane];
  float yr0[8], yr1[8], yi0[8], yi1[8];
#pragma unroll
  for (int k = 0; k < 8; ++k) {
    yr0[k] = cr0; yr1[k] = cr1; yi0[k] = ci0; yi1[k] = ci1;
  }
#pragma unroll 8
  for (int f = 0; f < 128; ++f) {
    float wa = r1T[f * 128 + lane], wb = r1T[f * 128 + 64 + lane];
    float wc = i1T[f * 128 + lane], wd = i1T[f * 128 + 64 + lane];
#pragma unroll
    for (int k2 = 0; k2 < 4; ++k2) {
      float4 v = A[k2 * 128 + f];
      yr0[2 * k2] += v.x * wa; yr1[2 * k2] += v.x * wb;
      yi0[2 * k2] += v.y * wc; yi1[2 * k2] += v.y * wd;
      yr0[2 * k2 + 1] += v.z * wa; yr1[2 * k2 + 1] += v.z * wb;
      yi0[2 * k2 + 1] += v.w * wc; yi1[2 * k2 + 1] += v.w * wd;
    }
  }
#pragma unroll
  for (int k = 0; k < 8; ++k) {
    float m0 = (yr0[k] >= 0.f) ? 1.f : 0.f;
    float m1 = (yr1[k] >= 0.f) ? 1.f : 0.f;
    yr0[k] *= m0; yi0[k] *= m0; yr1[k] *= m1; yi1[k] *= m1;
  }

  // stage output-layer inputs
#pragma unroll
  for (int k2 = 0; k2 < 4; ++k2) {
    A[k2 * 128 + lane] =
        make_float4(yr0[2 * k2], yi0[2 * k2], yr0[2 * k2 + 1], yi0[2 * k2 + 1]);
    A[k2 * 128 + 64 + lane] =
        make_float4(yr1[2 * k2], yi1[2 * k2], yr1[2 * k2 + 1], yi1[2 * k2 + 1]);
  }

  // ---- output: concat(real,imag) 256 -> 32 ----
  int o = lane & 31, hi = lane >> 5;
  float acc[8];
#pragma unroll
  for (int k = 0; k < 8; ++k) acc[k] = 0.f;
#pragma unroll 8
  for (int f = 0; f < 128; ++f) {
    float wv = owT[(hi ? 128 + f : f) * 32 + o];
#pragma unroll
    for (int k2 = 0; k2 < 4; ++k2) {
      float4 v = A[k2 * 128 + f];
      acc[2 * k2] += (hi ? v.y : v.x) * wv;
      acc[2 * k2 + 1] += (hi ? v.w : v.z) * wv;
    }
  }
  float obv = ob[o];
#pragma unroll
  for (int k = 0; k < 8; ++k) {
    acc[k] += __shfl_xor(acc[k], 32, 64);
    if (lane < 32) out[(size_t)(nb + k) * 32 + o] = acc[k] + obv;
  }
}

// ---------------- launch ----------------

extern "C" void kernel_launch(void* const* d_in, const int* in_sizes, int n_in,
                              void* d_out, int out_size, void* d_ws,
                              size_t ws_size, hipStream_t stream) {
  const float* realf = (const float*)d_in[0];
  const float* imagf = (const float*)d_in[1];
  const float* ent = (const float*)d_in[2];
  const float* ccf = (const float*)d_in[3];
  const float* wsym = (const float*)d_in[4];
  const float* q = (const float*)d_in[5];
  const float* encw = (const float*)d_in[6];
  const float* encb = (const float*)d_in[7];
  const float* rattw = (const float*)d_in[8];
  const float* rattb = (const float*)d_in[9];
  const float* iattw = (const float*)d_in[10];
  const float* iattb = (const float*)d_in[11];
  const float* r0w = (const float*)d_in[12];
  const float* r0b = (const float*)d_in[13];
  const float* r1w = (const float*)d_in[14];
  const float* r1b = (const float*)d_in[15];
  const float* i0w = (const float*)d_in[16];
  const float* i0b = (const float*)d_in[17];
  const float* i1w = (const float*)d_in[18];
  const float* i1b = (const float*)d_in[19];
  const float* ow = (const float*)d_in[20];
  const float* ob = (const float*)d_in[21];
  const int* row = (const int*)d_in[22];
  const int* col = (const int*)d_in[23];
  float* out = (float*)d_out;

  char* p = (char*)d_ws;
  auto alloc = [&](size_t bytes) -> void* {
    void* r = (void*)p;
    p += (bytes + 255) & ~(size_t)255;
    return r;
  };
  int* cnt = (int*)alloc(N_NODES * sizeof(int));
  int* offs = (int*)alloc((N_NODES + 1) * sizeof(int));
  int* col_s = (int*)alloc(N_EDGES * sizeof(int));
  float* wr_s = (float*)alloc(N_EDGES * sizeof(float));
  float* wi_s = (float*)alloc(N_EDGES * sizeof(float));
  size_t NF = (size_t)N_NODES * FDIM;
  float* R1 = (float*)alloc(NF * 4);
  float* R2 = (float*)alloc(NF * 4);
  float* R3 = (float*)alloc(NF * 4);
  float* I1 = (float*)alloc(NF * 4);
  float* I2 = (float*)alloc(NF * 4);
  float* I3 = (float*)alloc(NF * 4);
  float* r0T = (float*)alloc(64 * 128 * 4);
  float* i0T = (float*)alloc(64 * 128 * 4);
  float* r1T = (float*)alloc(128 * 128 * 4);
  float* i1T = (float*)alloc(128 * 128 * 4);
  float* owT = (float*)alloc(256 * 32 * 4);

  hipMemsetAsync(cnt, 0, N_NODES * sizeof(int), stream);
  prep_weights<<<64, 256, 0, stream>>>(r0w, i0w, r1w, i1w, ow, r0T, i0T, r1T,
                                       i1T, owT);
  hist_kernel<<<(N_EDGES + 255) / 256, 256, 0, stream>>>(row, cnt, N_EDGES);
  prefix_kernel<<<1, 1024, 0, stream>>>(cnt, offs, N_NODES, N_EDGES);
  scatter_kernel<<<(N_EDGES + 255) / 256, 256, 0, stream>>>(
      row, col, ent, ccf, wsym, encw, encb, q, cnt, col_s, wr_s, wi_s, N_EDGES);

  const int pgrid = (N_NODES + 3) / 4;  // 4 waves (nodes) per 256-thread block
  prop_kernel<<<pgrid, 256, 0, stream>>>(realf, imagf, R1, I1, offs, col_s,
                                         wr_s, wi_s, N_NODES);
  prop_kernel<<<pgrid, 256, 0, stream>>>(R1, I1, R2, I2, offs, col_s, wr_s,
                                         wi_s, N_NODES);
  prop_kernel<<<pgrid, 256, 0, stream>>>(R2, I2, R3, I3, offs, col_s, wr_s,
                                         wi_s, N_NODES);

  const int hgrid = (N_NODES / 8 + 3) / 4;  // 8 nodes/wave, 4 waves/block
  head_kernel<<<hgrid, 256, 0, stream>>>(
      realf, R1, R2, R3, imagf, I1, I2, I3, rattw, rattb, iattw, iattb, r0T,
      r0b, i0T, i0b, r1T, r1b, i1T, i1b, owT, ob, out, N_NODES);
}

// Round 3
// 579.840 us; speedup vs baseline: 1.4853x; 1.3652x over previous
//
#include <hip/hip_runtime.h>

#define N_NODES 50000
#define N_EDGES 800000
#define FDIM 64
#define NST 50000  // PT row stride (floats)

// ---------------- edge weight + CSR construction ----------------

__global__ __launch_bounds__(256) void hist_kernel(const int* __restrict__ row,
                                                   int* __restrict__ cnt, int E) {
  int e = blockIdx.x * 256 + threadIdx.x;
  if (e < E) atomicAdd(&cnt[row[e]], 1);
}

__global__ __launch_bounds__(1024) void prefix_kernel(int* __restrict__ cnt,
                                                      int* __restrict__ offs,
                                                      int n, int E) {
  __shared__ int tot[1024];
  int t = threadIdx.x;
  int CH = (n + 1023) >> 10;
  int b = t * CH;
  int e = min(b + CH, n);
  int s = 0;
  for (int i = b; i < e; ++i) s += cnt[i];
  tot[t] = s;
  __syncthreads();
  for (int d = 1; d < 1024; d <<= 1) {
    int add = (t >= d) ? tot[t - d] : 0;
    __syncthreads();
    tot[t] += add;
    __syncthreads();
  }
  int run = (t == 0) ? 0 : tot[t - 1];
  for (int i = b; i < e; ++i) {
    int h = cnt[i];
    offs[i] = run;
    cnt[i] = run;  // becomes the scatter cursor
    run += h;
  }
  if (t == 0) offs[n] = E;
}

__global__ __launch_bounds__(256) void scatter_kernel(
    const int* __restrict__ row, const int* __restrict__ col,
    const float* __restrict__ ent, const float* __restrict__ ccf,
    const float* __restrict__ wsym, const float* __restrict__ encw,
    const float* __restrict__ encb, const float* __restrict__ q,
    int* __restrict__ cursor, int* __restrict__ col_s,
    float2* __restrict__ ws, int E) {
  int e = blockIdx.x * 256 + threadIdx.x;
  if (e >= E) return;
  float se = encw[0] * ent[e] + encw[1] * ccf[e] + encb[0];
  float ph = q[0] * se;
  float sw, cw;
  sincosf(ph, &sw, &cw);
  float w = wsym[e];
  int pos = atomicAdd(&cursor[row[e]], 1);
  col_s[pos] = col[e];
  ws[pos] = make_float2(w * cw, w * sw);
}

// ---------------- weight transpose prep ----------------

__global__ __launch_bounds__(256) void prep_weights(
    const float* __restrict__ r0, const float* __restrict__ i0,
    const float* __restrict__ r1, const float* __restrict__ i1,
    float* __restrict__ r0T, float* __restrict__ i0T, float* __restrict__ r1T,
    float* __restrict__ i1T) {
  int t = blockIdx.x * 256 + threadIdx.x;
  if (t < 128 * 64) {  // [128 h][64 f] -> [64 f][128 h]
    int h = t / 64, f = t % 64;
    r0T[f * 128 + h] = r0[t];
    i0T[f * 128 + h] = i0[t];
  }
  if (t < 128 * 128) {  // [128 h][128 f] -> [128 f][128 h]
    int h = t / 128, f = t % 128;
    r1T[f * 128 + h] = r1[t];
    i1T[f * 128 + h] = i1[t];
  }
}

// ---------------- pack re/im into interleaved rows [node][2f | 2f+1] ------

__global__ __launch_bounds__(256) void pack_kernel(const float* __restrict__ re,
                                                   const float* __restrict__ im,
                                                   float2* __restrict__ X,
                                                   int total) {  // total = N*64
  int i = blockIdx.x * 256 + threadIdx.x;
  if (i < total) X[i] = make_float2(re[i], im[i]);
}

// ---------------- complex propagation: 2 edges/wave-iter ----------------
// X rows are [re0,im0,re1,im1,...] (128 floats). Lane l: half = l>>5 picks
// edge j+half; l&31 picks a float4 (2 features re+im). shfl_xor(32) combines.

__global__ __launch_bounds__(256) void prop_kernel(
    const float* __restrict__ X, float* __restrict__ Y,
    const int* __restrict__ offs, const int* __restrict__ col_s,
    const float2* __restrict__ ws, int n) {
  int wave = (int)((blockIdx.x * (size_t)blockDim.x + threadIdx.x) >> 6);
  int lane = threadIdx.x & 63;
  if (wave >= n) return;
  int half = lane >> 5, l5 = lane & 31;
  int beg = offs[wave], end = offs[wave + 1];
  float4 acc = make_float4(0.f, 0.f, 0.f, 0.f);
  int j = beg;
  for (; j + 4 <= end; j += 4) {
    int c0 = col_s[j + half];
    int c1 = col_s[j + 2 + half];
    float2 w0 = ws[j + half];
    float2 w1 = ws[j + 2 + half];
    float4 x0 = *(const float4*)&X[(size_t)c0 * 128 + l5 * 4];
    float4 x1 = *(const float4*)&X[(size_t)c1 * 128 + l5 * 4];
    acc.x += w0.x * x0.x - w0.y * x0.y;
    acc.y += w0.y * x0.x + w0.x * x0.y;
    acc.z += w0.x * x0.z - w0.y * x0.w;
    acc.w += w0.y * x0.z + w0.x * x0.w;
    acc.x += w1.x * x1.x - w1.y * x1.y;
    acc.y += w1.y * x1.x + w1.x * x1.y;
    acc.z += w1.x * x1.z - w1.y * x1.w;
    acc.w += w1.y * x1.z + w1.x * x1.w;
  }
  for (; j < end; j += 2) {
    int je = j + half;
    bool valid = je < end;
    int jc = valid ? je : beg;
    float2 w = ws[jc];
    float wr = valid ? w.x : 0.f;
    float wi = valid ? w.y : 0.f;
    int cc = col_s[jc];
    float4 x = *(const float4*)&X[(size_t)cc * 128 + l5 * 4];
    acc.x += wr * x.x - wi * x.y;
    acc.y += wi * x.x + wr * x.y;
    acc.z += wr * x.z - wi * x.w;
    acc.w += wi * x.z + wr * x.w;
  }
  acc.x += __shfl_xor(acc.x, 32, 64);
  acc.y += __shfl_xor(acc.y, 32, 64);
  acc.z += __shfl_xor(acc.z, 32, 64);
  acc.w += __shfl_xor(acc.w, 32, 64);
  if (lane < 32) *(float4*)&Y[(size_t)wave * 128 + l5 * 4] = acc;
}

// ---------------- attention pooling -> PT [128 f][NST nodes] ----------------

__device__ __forceinline__ float wave_sum(float v) {
#pragma unroll
  for (int d = 32; d > 0; d >>= 1) v += __shfl_xor(v, d, 64);
  return v;
}

__global__ __launch_bounds__(256) void pool_kernel(
    const float* __restrict__ R0f, const float* __restrict__ I0f,
    const float* __restrict__ X1, const float* __restrict__ X2,
    const float* __restrict__ X3, const float* __restrict__ rattw,
    const float* __restrict__ rattb, const float* __restrict__ iattw,
    const float* __restrict__ iattb, float* __restrict__ PT, int n) {
  __shared__ float pt[128 * 65];  // 33.3 KB, [f-row][node-col], stride 65
  int wid = threadIdx.x >> 6, lane = threadIdx.x & 63;
  int nb = blockIdx.x * 64;
  float aw = rattw[lane], bw = iattw[lane];
  float rb0 = rattb[0], ib0 = iattb[0];
  for (int k = 0; k < 16; ++k) {
    int ln = wid * 16 + k;
    int nc = min(nb + ln, n - 1);
    float r0 = R0f[(size_t)nc * 64 + lane];
    float q0 = I0f[(size_t)nc * 64 + lane];
    size_t base = (size_t)nc * 128 + 2 * lane;
    float2 v1 = *(const float2*)&X1[base];
    float2 v2 = *(const float2*)&X2[base];
    float2 v3 = *(const float2*)&X3[base];
    float ra0 = wave_sum(r0 * aw) + rb0;
    float ra1 = wave_sum(v1.x * aw) + rb0;
    float ra2 = wave_sum(v2.x * aw) + rb0;
    float ra3 = wave_sum(v3.x * aw) + rb0;
    float ia0 = wave_sum(q0 * bw) + ib0;
    float ia1 = wave_sum(v1.y * bw) + ib0;
    float ia2 = wave_sum(v2.y * bw) + ib0;
    float ia3 = wave_sum(v3.y * bw) + ib0;
    float s0 = 1.f / (1.f + __expf(-ra0));
    float s1 = 1.f / (1.f + __expf(-ra1));
    float s2 = 1.f / (1.f + __expf(-ra2));
    float s3 = 1.f / (1.f + __expf(-ra3));
    float t0 = 1.f / (1.f + __expf(-ia0));
    float t1 = 1.f / (1.f + __expf(-ia1));
    float t2 = 1.f / (1.f + __expf(-ia2));
    float t3 = 1.f / (1.f + __expf(-ia3));
    float mR = fmaxf(fmaxf(s0, s1), fmaxf(s2, s3));
    float e0 = __expf(s0 - mR), e1 = __expf(s1 - mR), e2 = __expf(s2 - mR),
          e3 = __expf(s3 - mR);
    float invR = 1.f / (e0 + e1 + e2 + e3);
    float mI = fmaxf(fmaxf(t0, t1), fmaxf(t2, t3));
    float g0 = __expf(t0 - mI), g1 = __expf(t1 - mI), g2 = __expf(t2 - mI),
          g3 = __expf(t3 - mI);
    float invI = 1.f / (g0 + g1 + g2 + g3);
    float pr = (r0 * e0 + v1.x * e1 + v2.x * e2 + v3.x * e3) * invR;
    float pi = (q0 * g0 + v1.y * g1 + v2.y * g2 + v3.y * g3) * invI;
    pt[lane * 65 + ln] = pr;
    pt[(64 + lane) * 65 + ln] = pi;
  }
  __syncthreads();
  int c = threadIdx.x & 63, fr = threadIdx.x >> 6;
  for (int r = 0; r < 32; ++r) {
    int f = fr * 32 + r;
    int nd = nb + c;
    if (nd < n) PT[(size_t)f * NST + nd] = pt[f * 65 + c];
  }
}

// ---------------- fused MLP: lane=node, s_load weights, LDS transpose ------

__global__ __launch_bounds__(256) void mlp_kernel(
    const float* __restrict__ PT, const float* __restrict__ r0T,
    const float* __restrict__ r0b, const float* __restrict__ i0T,
    const float* __restrict__ i0b, const float* __restrict__ r1T,
    const float* __restrict__ r1b, const float* __restrict__ i1T,
    const float* __restrict__ i1b, const float* __restrict__ ow,
    const float* __restrict__ ob, float* __restrict__ out, int n) {
  __shared__ float zt[256 * 65];  // 66.56 KB; z-tile, later partial buffer
  int lane = threadIdx.x & 63;
  int wid = threadIdx.x >> 6;
  int h0 = __builtin_amdgcn_readfirstlane(wid * 32);  // SGPR -> s_load weights
  int nb = blockIdx.x * 64;
  int node = min(nb + lane, n - 1);  // clamp: tail lanes recompute node n-1

  // ---- layer 0: 64 -> 128 (re,im independent; mask couples) ----
  float zr[32], zi[32];
#pragma unroll
  for (int j = 0; j < 32; ++j) {
    zr[j] = r0b[h0 + j];
    zi[j] = i0b[h0 + j];
  }
  for (int f = 0; f < 64; ++f) {
    float ar = PT[(size_t)f * NST + node];
    float ai = PT[(size_t)(64 + f) * NST + node];
    const float* wr = &r0T[f * 128 + h0];
    const float* wi = &i0T[f * 128 + h0];
#pragma unroll
    for (int j = 0; j < 32; ++j) {
      zr[j] += ar * wr[j];
      zi[j] += ai * wi[j];
    }
  }
#pragma unroll
  for (int j = 0; j < 32; ++j) {
    float m = (zr[j] >= 0.f) ? 1.f : 0.f;
    zt[(h0 + j) * 65 + lane] = zr[j] * m;
    zt[(128 + h0 + j) * 65 + lane] = zi[j] * m;
  }
  __syncthreads();

  // ---- layer 1: 128 -> 128 ----
  float yr[32], yi[32];
#pragma unroll
  for (int j = 0; j < 32; ++j) {
    yr[j] = r1b[h0 + j];
    yi[j] = i1b[h0 + j];
  }
  for (int f = 0; f < 128; ++f) {
    float ar = zt[f * 65 + lane];
    float ai = zt[(128 + f) * 65 + lane];
    const float* wr = &r1T[f * 128 + h0];
    const float* wi = &i1T[f * 128 + h0];
#pragma unroll
    for (int j = 0; j < 32; ++j) {
      yr[j] += ar * wr[j];
      yi[j] += ai * wi[j];
    }
  }
#pragma unroll
  for (int j = 0; j < 32; ++j) {
    float m = (yr[j] >= 0.f) ? 1.f : 0.f;
    yr[j] *= m;
    yi[j] *= m;
  }

  // ---- output partials over this wave's 32 h (re+im) ----
  float po[32];
#pragma unroll 4
  for (int o = 0; o < 32; ++o) {
    const float* wrow = &ow[o * 256];
    float t = 0.f;
#pragma unroll
    for (int j = 0; j < 32; ++j)
      t += yr[j] * wrow[h0 + j] + yi[j] * wrow[128 + h0 + j];
    po[o] = t;
  }
  __syncthreads();  // all waves done reading zt
  float* pz = &zt[wid * (64 * 33)];  // [64 node][33] per wave, 33.8 KB total
#pragma unroll
  for (int o = 0; o < 32; ++o) pz[lane * 33 + o] = po[o];
  __syncthreads();

  for (int idx = threadIdx.x; idx < 2048; idx += 256) {
    int ln = idx >> 5, o = idx & 31;
    float s = zt[0 * 2112 + ln * 33 + o] + zt[1 * 2112 + ln * 33 + o] +
              zt[2 * 2112 + ln * 33 + o] + zt[3 * 2112 + ln * 33 + o] + ob[o];
    int nd = nb + ln;
    if (nd < n) out[(size_t)nd * 32 + o] = s;
  }
}

// ---------------- launch ----------------

extern "C" void kernel_launch(void* const* d_in, const int* in_sizes, int n_in,
                              void* d_out, int out_size, void* d_ws,
                              size_t ws_size, hipStream_t stream) {
  const float* realf = (const float*)d_in[0];
  const float* imagf = (const float*)d_in[1];
  const float* ent = (const float*)d_in[2];
  const float* ccf = (const float*)d_in[3];
  const float* wsym = (const float*)d_in[4];
  const float* q = (const float*)d_in[5];
  const float* encw = (const float*)d_in[6];
  const float* encb = (const float*)d_in[7];
  const float* rattw = (const float*)d_in[8];
  const float* rattb = (const float*)d_in[9];
  const float* iattw = (const float*)d_in[10];
  const float* iattb = (const float*)d_in[11];
  const float* r0w = (const float*)d_in[12];
  const float* r0b = (const float*)d_in[13];
  const float* r1w = (const float*)d_in[14];
  const float* r1b = (const float*)d_in[15];
  const float* i0w = (const float*)d_in[16];
  const float* i0b = (const float*)d_in[17];
  const float* i1w = (const float*)d_in[18];
  const float* i1b = (const float*)d_in[19];
  const float* ow = (const float*)d_in[20];
  const float* ob = (const float*)d_in[21];
  const int* row = (const int*)d_in[22];
  const int* col = (const int*)d_in[23];
  float* out = (float*)d_out;

  char* p = (char*)d_ws;
  auto alloc = [&](size_t bytes) -> void* {
    void* r = (void*)p;
    p += (bytes + 255) & ~(size_t)255;
    return r;
  };
  int* cnt = (int*)alloc(N_NODES * sizeof(int));
  int* offs = (int*)alloc((N_NODES + 1) * sizeof(int));
  int* col_s = (int*)alloc(N_EDGES * sizeof(int));
  float2* ws2 = (float2*)alloc(N_EDGES * sizeof(float2));
  size_t NX = (size_t)N_NODES * 128 * sizeof(float);  // interleaved level
  float* X0 = (float*)alloc(NX);
  float* X1 = (float*)alloc(NX);
  float* X2 = (float*)alloc(NX);
  float* X3 = (float*)alloc(NX);
  float* PT = (float*)alloc((size_t)128 * NST * sizeof(float));
  float* r0T = (float*)alloc(64 * 128 * 4);
  float* i0T = (float*)alloc(64 * 128 * 4);
  float* r1T = (float*)alloc(128 * 128 * 4);
  float* i1T = (float*)alloc(128 * 128 * 4);

  hipMemsetAsync(cnt, 0, N_NODES * sizeof(int), stream);
  prep_weights<<<64, 256, 0, stream>>>(r0w, i0w, r1w, i1w, r0T, i0T, r1T, i1T);
  hist_kernel<<<(N_EDGES + 255) / 256, 256, 0, stream>>>(row, cnt, N_EDGES);
  prefix_kernel<<<1, 1024, 0, stream>>>(cnt, offs, N_NODES, N_EDGES);
  scatter_kernel<<<(N_EDGES + 255) / 256, 256, 0, stream>>>(
      row, col, ent, ccf, wsym, encw, encb, q, cnt, col_s, ws2, N_EDGES);
  pack_kernel<<<(N_NODES * 64 + 255) / 256, 256, 0, stream>>>(
      realf, imagf, (float2*)X0, N_NODES * 64);

  const int pgrid = (N_NODES + 3) / 4;  // 4 waves (nodes) per 256-thread block
  prop_kernel<<<pgrid, 256, 0, stream>>>(X0, X1, offs, col_s, ws2, N_NODES);
  prop_kernel<<<pgrid, 256, 0, stream>>>(X1, X2, offs, col_s, ws2, N_NODES);
  prop_kernel<<<pgrid, 256, 0, stream>>>(X2, X3, offs, col_s, ws2, N_NODES);

  const int hgrid = (N_NODES + 63) / 64;  // 64 nodes per 256-thread block
  pool_kernel<<<hgrid, 256, 0, stream>>>(realf, imagf, X1, X2, X3, rattw,
                                         rattb, iattw, iattb, PT, N_NODES);
  mlp_kernel<<<hgrid, 256, 0, stream>>>(PT, r0T, r0b, i0T, i0b, r1T, r1b, i1T,
                                        i1b, ow, ob, out, N_NODES);
}